// Round 1
// baseline (321.279 us; speedup 1.0000x reference)
//
#include <hip/hip_runtime.h>
#include <math.h>

#define HH 256
#define WW 256
#define BC 512   // B*C = 8*64
#define QN 100

// ---------------------------------------------------------------------------
// Kernel 1: per-(b,c) 18x100 GEMM + q output + derived conv coefficients.
// coef layout per bc (stride 32 floats): [0..8]=former, [9..17]=wk,
// [18..26]=|wk|, [27..29]=column sums of wk (the 1x3 kernel).
// ---------------------------------------------------------------------------
__global__ __launch_bounds__(128) void prep_kernel(
    const float* __restrict__ query,   // (100, 8, 64) = (100, 512)
    const float* __restrict__ Wl,      // (18, 100)
    const float* __restrict__ bl,      // (18,)
    const float* __restrict__ Wd,      // (100, 18)
    const float* __restrict__ bd,      // (100,)
    float* __restrict__ qout,          // (100, 512) region of d_out
    float* __restrict__ coef)          // (512, 32) in d_ws
{
    const int bc = blockIdx.x;
    const int t  = threadIdx.x;
    __shared__ float qcol[QN];
    __shared__ float c18[18];

    if (t < QN) qcol[t] = query[t * BC + bc];
    __syncthreads();

    if (t < 18) {
        float acc = bl[t];
        const float* wrow = Wl + t * QN;
        #pragma unroll 4
        for (int qi = 0; qi < QN; ++qi) acc += qcol[qi] * wrow[qi];
        c18[t] = acc;
    }
    __syncthreads();

    if (t < QN) {
        float acc = bd[t];
        const float* wrow = Wd + t * 18;
        #pragma unroll
        for (int k = 0; k < 18; ++k) acc += c18[k] * wrow[k];
        qout[t * BC + bc] = acc;   // q.transpose(2,0,1) layout
    }

    if (t < 18) {
        coef[bc * 32 + t] = c18[t];                      // former / wk
    } else if (t < 27) {
        coef[bc * 32 + t] = fabsf(c18[t - 9]);           // |wk|
    } else if (t < 30) {
        int j = t - 27;
        coef[bc * 32 + t] = c18[9 + j] + c18[12 + j] + c18[15 + j]; // colsum
    }
}

// ---------------------------------------------------------------------------
// Kernel 2: fused depthwise pipeline over one 32x32 tile of one (b,c) plane.
//   y_temp = conv3x3(value, former)            [needs value halo+1]
//   diff   = exp(-(value - y_temp)^2)          [zero outside image]
//   y      = y_temp - (conv3x3(value*diff, wk) - conv1x3(value*diff, colsum))
//                      / (conv3x3(diff, |wk|) + 1e-10)
// Two-level halo: value staged 36x36, diff/y_temp computed 34x34, output 32x32.
// ---------------------------------------------------------------------------
__global__ __launch_bounds__(256) void fused_kernel(
    const float* __restrict__ value,   // (512, 256, 256)
    const float* __restrict__ coef,    // (512, 32)
    float* __restrict__ yout)          // (512, 256, 256) region of d_out
{
    const int bc = blockIdx.z;
    const int h0 = blockIdx.y * 32;
    const int w0 = blockIdx.x * 32;
    const int tid = threadIdx.x;

    __shared__ float sval[36][37];   // value, origin (h0-2, w0-2)
    __shared__ float sdiff[34][36];  // diff,  origin (h0-1, w0-1)
    __shared__ float syt[34][36];    // y_temp, same origin
    __shared__ float sc[32];

    if (tid < 30) sc[tid] = coef[bc * 32 + tid];

    const float* vp = value + (size_t)bc * (HH * WW);

    // ---- stage value tile with 2-halo (36x36) ----
    #pragma unroll
    for (int it = 0; it < 6; ++it) {
        int idx = tid + it * 256;
        if (idx < 36 * 36) {
            int r = idx / 36, c = idx - r * 36;
            int h = h0 - 2 + r, w = w0 - 2 + c;
            float v = 0.f;
            if ((unsigned)h < HH && (unsigned)w < WW) v = vp[h * WW + w];
            sval[r][c] = v;
        }
    }
    __syncthreads();

    // ---- phase 2: y_temp & diff over 34x34 ----
    float f[9];
    #pragma unroll
    for (int i = 0; i < 9; ++i) f[i] = sc[i];

    #pragma unroll
    for (int it = 0; it < 5; ++it) {
        int idx = tid + it * 256;
        if (idx < 34 * 34) {
            int r = idx / 34, c = idx - r * 34;
            float yt = 0.f;
            #pragma unroll
            for (int i = 0; i < 3; ++i)
                #pragma unroll
                for (int j = 0; j < 3; ++j)
                    yt += f[i * 3 + j] * sval[r + i][c + j];
            float v = sval[r + 1][c + 1];
            float e = v - yt;
            float d = __expf(-e * e);
            int h = h0 - 1 + r, w = w0 - 1 + c;
            if ((unsigned)h >= HH || (unsigned)w >= WW) d = 0.f; // SAME zero-pad
            sdiff[r][c] = d;
            syt[r][c]   = yt;
        }
    }
    __syncthreads();

    // ---- phase 3: each thread computes a 1x4 strip of the 32x32 tile ----
    float wk[9], awk[9], wsum[3];
    #pragma unroll
    for (int i = 0; i < 9; ++i) { wk[i] = sc[9 + i]; awk[i] = sc[18 + i]; }
    #pragma unroll
    for (int j = 0; j < 3; ++j) wsum[j] = sc[27 + j];

    const int r  = tid >> 3;        // 0..31 tile row
    const int c0 = (tid & 7) * 4;   // 0,4,...,28 strip start col

    // register-stage the overlapping taps for 4 consecutive output columns
    float dreg[3][6], vreg[3][6];
    #pragma unroll
    for (int i = 0; i < 3; ++i)
        #pragma unroll
        for (int j = 0; j < 6; ++j) {
            dreg[i][j] = sdiff[r + i][c0 + j];
            vreg[i][j] = sval[r + 1 + i][c0 + 1 + j];
        }

    float4 outv;
    float* outp = &outv.x;
    #pragma unroll
    for (int p = 0; p < 4; ++p) {
        float yd9 = 1e-10f;
        float rs  = 0.f;
        #pragma unroll
        for (int i = 0; i < 3; ++i)
            #pragma unroll
            for (int j = 0; j < 3; ++j) {
                float dd = dreg[i][p + j];
                yd9 += dd * awk[i * 3 + j];
                rs  += dd * vreg[i][p + j] * wk[i * 3 + j];
            }
        float rd = 0.f;
        #pragma unroll
        for (int j = 0; j < 3; ++j)
            rd += dreg[1][p + j] * vreg[1][p + j] * wsum[j];
        float yt = syt[r + 1][c0 + 1 + p];
        outp[p] = yt - (rs - rd) / yd9;
    }

    float* dst = yout + (size_t)bc * (HH * WW) + (size_t)(h0 + r) * WW + (w0 + c0);
    *reinterpret_cast<float4*>(dst) = outv;
}

// ---------------------------------------------------------------------------
extern "C" void kernel_launch(void* const* d_in, const int* in_sizes, int n_in,
                              void* d_out, int out_size, void* d_ws, size_t ws_size,
                              hipStream_t stream) {
    const float* query = (const float*)d_in[0];   // (100,8,64)
    const float* value = (const float*)d_in[1];   // (8,64,256,256)
    // d_in[2..4]: unused scalars
    const float* Wl    = (const float*)d_in[5];   // (18,100)
    const float* bl    = (const float*)d_in[6];   // (18,)
    const float* Wd    = (const float*)d_in[7];   // (100,18)
    const float* bd    = (const float*)d_in[8];   // (100,)

    float* out   = (float*)d_out;
    float* qout  = out;                 // first 100*512 floats
    float* yout  = out + QN * BC;       // then 512*256*256 floats
    float* coef  = (float*)d_ws;        // 512*32 floats = 64 KB

    prep_kernel<<<BC, 128, 0, stream>>>(query, Wl, bl, Wd, bd, qout, coef);

    dim3 grid(WW / 32, HH / 32, BC);
    fused_kernel<<<grid, 256, 0, stream>>>(value, coef, yout);
}

// Round 2
// 321.083 us; speedup vs baseline: 1.0006x; 1.0006x over previous
//
#include <hip/hip_runtime.h>
#include <math.h>

#define HH 256
#define WW 256
#define BC 512   // B*C = 8*64
#define QN 100

// ---------------------------------------------------------------------------
// Kernel 1: per-(b,c) 18x100 GEMM + q output + derived conv coefficients.
// coef layout per bc (stride 32 floats): [0..8]=former, [9..17]=wk,
// [18..26]=|wk|, [27..29]=column sums of wk (the 1x3 kernel).
// ---------------------------------------------------------------------------
__global__ __launch_bounds__(128) void prep_kernel(
    const float* __restrict__ query,   // (100, 8, 64) = (100, 512)
    const float* __restrict__ Wl,      // (18, 100)
    const float* __restrict__ bl,      // (18,)
    const float* __restrict__ Wd,      // (100, 18)
    const float* __restrict__ bd,      // (100,)
    float* __restrict__ qout,          // (100, 512) region of d_out
    float* __restrict__ coef)          // (512, 32) in d_ws
{
    const int bc = blockIdx.x;
    const int t  = threadIdx.x;
    __shared__ float qcol[QN];
    __shared__ float c18[18];

    if (t < QN) qcol[t] = query[t * BC + bc];
    __syncthreads();

    if (t < 18) {
        float acc = bl[t];
        const float* wrow = Wl + t * QN;
        #pragma unroll 4
        for (int qi = 0; qi < QN; ++qi) acc += qcol[qi] * wrow[qi];
        c18[t] = acc;
    }
    __syncthreads();

    if (t < QN) {
        float acc = bd[t];
        const float* wrow = Wd + t * 18;
        #pragma unroll
        for (int k = 0; k < 18; ++k) acc += c18[k] * wrow[k];
        qout[t * BC + bc] = acc;   // q.transpose(2,0,1) layout
    }

    if (t < 18) {
        coef[bc * 32 + t] = c18[t];                      // former / wk
    } else if (t < 27) {
        coef[bc * 32 + t] = fabsf(c18[t - 9]);           // |wk|
    } else if (t < 30) {
        int j = t - 27;
        coef[bc * 32 + t] = c18[9 + j] + c18[12 + j] + c18[15 + j]; // colsum
    }
}

// load 8 consecutive LDS floats as two b128s
#define LD8(dst, ptr0) { \
    float4 _x = *(const float4*)(ptr0); \
    float4 _y = *(const float4*)((ptr0) + 4); \
    dst[0]=_x.x; dst[1]=_x.y; dst[2]=_x.z; dst[3]=_x.w; \
    dst[4]=_y.x; dst[5]=_y.y; dst[6]=_y.z; dst[7]=_y.w; }

// ---------------------------------------------------------------------------
// Kernel 2: fused depthwise pipeline over one 32x32 tile of one (b,c) plane.
// LDS: sval 36x36 (value, origin h0-2,w0-2); sdiff 34x36 (diff, origin h0-1).
// All hot LDS access is ds_read_b128/ds_write_b128; with c0 = 4*(tid&7) the
// bank-quad distribution is uniform for any row stride ≡ 0 (mod 4).
// y_temp is recomputed in phase 3 from registers (no syt array).
// ---------------------------------------------------------------------------
__global__ __launch_bounds__(256) void fused_kernel(
    const float* __restrict__ value,   // (512, 256, 256)
    const float* __restrict__ coef,    // (512, 32)
    float* __restrict__ yout)          // (512, 256, 256) region of d_out
{
    const int bc = blockIdx.z;
    const int h0 = blockIdx.y * 32;
    const int w0 = blockIdx.x * 32;
    const int tid = threadIdx.x;

    __shared__ __align__(16) float sval[36][36];
    __shared__ __align__(16) float sdiff[34][36];

    // ---- coefficients: uniform address -> scalar loads, no LDS needed ----
    const float* cp = coef + bc * 32;
    float fco[9], wk[9], awk[9], ws[3];
    #pragma unroll
    for (int i = 0; i < 9; ++i) { fco[i] = cp[i]; wk[i] = cp[9 + i]; awk[i] = cp[18 + i]; }
    ws[0] = cp[27]; ws[1] = cp[28]; ws[2] = cp[29];

    const float* vp = value + (size_t)bc * (HH * WW);

    // ---- phase 1: stage value tile with 2-halo (36x36) ----
    #pragma unroll
    for (int it = 0; it < 6; ++it) {
        int idx = tid + it * 256;
        if (idx < 36 * 36) {
            int r = idx / 36, c = idx - r * 36;
            int h = h0 - 2 + r, w = w0 - 2 + c;
            float v = 0.f;
            if ((unsigned)h < HH && (unsigned)w < WW) v = vp[h * WW + w];
            sval[r][c] = v;
        }
    }
    __syncthreads();

    const int r  = tid >> 3;          // 0..31
    const int c0 = (tid & 7) << 2;    // 0,4,...,28

    // ---- phase 2 main: diff over rows 0..31 x cols 0..31 (vectorized) ----
    {
        float b0[8], b1[8], b2[8];
        LD8(b0, &sval[r][c0]);
        LD8(b1, &sval[r + 1][c0]);
        LD8(b2, &sval[r + 2][c0]);

        float4 dq;
        float* dd = &dq.x;
        #pragma unroll
        for (int p = 0; p < 4; ++p) {
            float yt = 0.f;
            #pragma unroll
            for (int j = 0; j < 3; ++j)
                yt += fco[j] * b0[p + j] + fco[3 + j] * b1[p + j] + fco[6 + j] * b2[p + j];
            float v = b1[p + 1];
            float e = v - yt;
            float d = __expf(-e * e);
            int h = h0 - 1 + r, w = w0 - 1 + c0 + p;
            if ((unsigned)h >= HH || (unsigned)w >= WW) d = 0.f; // SAME zero-pad
            dd[p] = d;
        }
        *(float4*)&sdiff[r][c0] = dq;
    }

    // ---- phase 2 edge: rows 32..33 (cols 0..33) + cols 32..33 (rows 0..31) ----
    if (tid < 132) {
        int rr, cc;
        if (tid < 68) { rr = 32 + (tid >= 34 ? 1 : 0); cc = tid - (tid >= 34 ? 34 : 0); }
        else          { int ee = tid - 68; rr = ee >> 1; cc = 32 + (ee & 1); }
        float yt = 0.f;
        #pragma unroll
        for (int i = 0; i < 3; ++i)
            #pragma unroll
            for (int j = 0; j < 3; ++j)
                yt += fco[i * 3 + j] * sval[rr + i][cc + j];
        float v = sval[rr + 1][cc + 1];
        float e = v - yt;
        float d = __expf(-e * e);
        int h = h0 - 1 + rr, w = w0 - 1 + cc;
        if ((unsigned)h >= HH || (unsigned)w >= WW) d = 0.f;
        sdiff[rr][cc] = d;
    }
    __syncthreads();

    // ---- phase 3: each thread computes a 1x4 output strip ----
    {
        float a0[8], a1[8], a2[8];   // sdiff rows r..r+2
        float q0[8], q1[8], q2[8];   // sval  rows r+1..r+3
        LD8(a0, &sdiff[r][c0]);
        LD8(a1, &sdiff[r + 1][c0]);
        LD8(a2, &sdiff[r + 2][c0]);
        LD8(q0, &sval[r + 1][c0]);
        LD8(q1, &sval[r + 2][c0]);
        LD8(q2, &sval[r + 3][c0]);

        // vd products, shared across the 4 outputs
        float pd0[6], pd1[6], pd2[6];
        #pragma unroll
        for (int j = 0; j < 6; ++j) {
            pd0[j] = a0[j] * q0[j + 1];
            pd1[j] = a1[j] * q1[j + 1];
            pd2[j] = a2[j] * q2[j + 1];
        }

        float4 outv;
        float* outp = &outv.x;
        #pragma unroll
        for (int p = 0; p < 4; ++p) {
            float yt  = 0.f;
            float yd9 = 1e-10f;
            float rs  = 0.f;
            float rd  = 0.f;
            #pragma unroll
            for (int j = 0; j < 3; ++j) {
                yt  += fco[j] * q0[p + 1 + j] + fco[3 + j] * q1[p + 1 + j] + fco[6 + j] * q2[p + 1 + j];
                yd9 += awk[j] * a0[p + j]     + awk[3 + j] * a1[p + j]     + awk[6 + j] * a2[p + j];
                rs  += wk[j]  * pd0[p + j]    + wk[3 + j]  * pd1[p + j]    + wk[6 + j]  * pd2[p + j];
                rd  += ws[j]  * pd1[p + j];
            }
            outp[p] = yt - (rs - rd) / yd9;
        }

        float* dst = yout + (size_t)bc * (HH * WW) + (size_t)(h0 + r) * WW + (w0 + c0);
        *reinterpret_cast<float4*>(dst) = outv;
    }
}

// ---------------------------------------------------------------------------
extern "C" void kernel_launch(void* const* d_in, const int* in_sizes, int n_in,
                              void* d_out, int out_size, void* d_ws, size_t ws_size,
                              hipStream_t stream) {
    const float* query = (const float*)d_in[0];   // (100,8,64)
    const float* value = (const float*)d_in[1];   // (8,64,256,256)
    // d_in[2..4]: unused scalars
    const float* Wl    = (const float*)d_in[5];   // (18,100)
    const float* bl    = (const float*)d_in[6];   // (18,)
    const float* Wd    = (const float*)d_in[7];   // (100,18)
    const float* bd    = (const float*)d_in[8];   // (100,)

    float* out   = (float*)d_out;
    float* qout  = out;                 // first 100*512 floats
    float* yout  = out + QN * BC;       // then 512*256*256 floats
    float* coef  = (float*)d_ws;        // 512*32 floats = 64 KB

    prep_kernel<<<BC, 128, 0, stream>>>(query, Wl, bl, Wd, bd, qout, coef);

    dim3 grid(WW / 32, HH / 32, BC);
    fused_kernel<<<grid, 256, 0, stream>>>(value, coef, yout);
}

// Round 3
// 309.643 us; speedup vs baseline: 1.0376x; 1.0369x over previous
//
#include <hip/hip_runtime.h>
#include <math.h>

#define HH 256
#define WW 256
#define BC 512   // B*C = 8*64
#define QN 100

// ---------------------------------------------------------------------------
// Kernel 1: per-(b,c) 18x100 GEMM + q output + derived conv coefficients.
// coef layout per bc (stride 32 floats): [0..8]=former, [9..17]=wk,
// [18..26]=|wk|, [27..29]=column sums of wk (the 1x3 kernel).
// ---------------------------------------------------------------------------
__global__ __launch_bounds__(128) void prep_kernel(
    const float* __restrict__ query,   // (100, 8, 64) = (100, 512)
    const float* __restrict__ Wl,      // (18, 100)
    const float* __restrict__ bl,      // (18,)
    const float* __restrict__ Wd,      // (100, 18)
    const float* __restrict__ bd,      // (100,)
    float* __restrict__ qout,          // (100, 512) region of d_out
    float* __restrict__ coef)          // (512, 32) in d_ws
{
    const int bc = blockIdx.x;
    const int t  = threadIdx.x;
    __shared__ float qcol[QN];
    __shared__ float c18[18];

    if (t < QN) qcol[t] = query[t * BC + bc];
    __syncthreads();

    if (t < 18) {
        float acc = bl[t];
        const float* wrow = Wl + t * QN;
        #pragma unroll 4
        for (int qi = 0; qi < QN; ++qi) acc += qcol[qi] * wrow[qi];
        c18[t] = acc;
    }
    __syncthreads();

    if (t < QN) {
        float acc = bd[t];
        const float* wrow = Wd + t * 18;
        #pragma unroll
        for (int k = 0; k < 18; ++k) acc += c18[k] * wrow[k];
        qout[t * BC + bc] = acc;   // q.transpose(2,0,1) layout
    }

    if (t < 18) {
        coef[bc * 32 + t] = c18[t];                      // former / wk
    } else if (t < 27) {
        coef[bc * 32 + t] = fabsf(c18[t - 9]);           // |wk|
    } else if (t < 30) {
        int j = t - 27;
        coef[bc * 32 + t] = c18[9 + j] + c18[12 + j] + c18[15 + j]; // colsum
    }
}

// ---------------------------------------------------------------------------
// Kernel 2: fused depthwise pipeline, 64x64 tile per block, 256 threads.
// All hot LDS traffic is lane-contiguous b32 (lane = column): stride-1 across
// the wave = 2 lanes/bank = conflict-free (m136).
//   sval[r][c]  = value(h0-2+r, w0-2+c)   r<68, c<68  (zero outside image)
//   sdiff[r][c] = diff (h0-1+r, w0-1+c)   r<66, c<66  (zero outside image)
// Phase 2: each wave computes a contiguous band of sdiff rows with a rolling
// 3-row register window. Phase 3: each wave computes 16 output rows; lane x
// owns column x with rolling sd/sv/vd windows.
// ---------------------------------------------------------------------------
__global__ __launch_bounds__(256) void fused_kernel(
    const float* __restrict__ value,   // (512, 256, 256)
    const float* __restrict__ coef,    // (512, 32)
    float* __restrict__ yout)          // (512, 256, 256) region of d_out
{
    const int bc  = blockIdx.z;
    const int h0  = blockIdx.y * 64;
    const int w0  = blockIdx.x * 64;
    const int tid = threadIdx.x;
    const int wave = tid >> 6;
    const int lane = tid & 63;

    __shared__ __align__(16) float sval[68][68];
    __shared__ __align__(16) float sdiff[66][68];

    // coefficients: block-uniform address -> scalar (SGPR) loads
    const float* cp = coef + bc * 32;
    float fco[9], wk[9], awk[9], ws[3];
    #pragma unroll
    for (int i = 0; i < 9; ++i) { fco[i] = cp[i]; wk[i] = cp[9 + i]; awk[i] = cp[18 + i]; }
    ws[0] = cp[27]; ws[1] = cp[28]; ws[2] = cp[29];

    const float* vp = value + (size_t)bc * (HH * WW);

    // ---- phase 1: stage value 68x68 (origin h0-2, w0-2), float2 chunks ----
    #pragma unroll
    for (int it = 0; it < 10; ++it) {
        int idx = tid + it * 256;
        if (idx < 68 * 34) {
            int r = idx / 34;
            int m = idx - r * 34;
            int h = h0 - 2 + r;
            int w = w0 - 2 + 2 * m;
            float2 v = make_float2(0.f, 0.f);
            if ((unsigned)h < HH) {
                const float* rowp = vp + h * WW;
                if ((unsigned)w < WW)       v.x = rowp[w];
                if ((unsigned)(w + 1) < WW) v.y = rowp[w + 1];
            }
            *(float2*)&sval[r][2 * m] = v;
        }
    }
    __syncthreads();

    // ---- phase 2 main: sdiff cols 0..63, rolling 3-row window per wave ----
    {
        const int lo = (wave < 2) ? 17 * wave : 34 + 16 * (wave - 2);
        const int hi = (wave < 2) ? lo + 17 : lo + 16;
        const int x  = lane;
        float t00 = sval[lo][x],     t01 = sval[lo][x + 1],     t02 = sval[lo][x + 2];
        float t10 = sval[lo + 1][x], t11 = sval[lo + 1][x + 1], t12 = sval[lo + 1][x + 2];
        for (int r = lo; r < hi; ++r) {
            float t20 = sval[r + 2][x], t21 = sval[r + 2][x + 1], t22 = sval[r + 2][x + 2];
            float yt = fco[0]*t00 + fco[1]*t01 + fco[2]*t02
                     + fco[3]*t10 + fco[4]*t11 + fco[5]*t12
                     + fco[6]*t20 + fco[7]*t21 + fco[8]*t22;
            float e = t11 - yt;
            float d = __expf(-e * e);
            if ((unsigned)(h0 - 1 + r) >= HH || (unsigned)(w0 - 1 + x) >= WW) d = 0.f;
            sdiff[r][x] = d;
            t00 = t10; t01 = t11; t02 = t12;
            t10 = t20; t11 = t21; t12 = t22;
        }
    }

    // ---- phase 2 edge: sdiff cols 64,65 for all 66 rows ----
    if (tid < 132) {
        int r = tid >> 1;
        int c = 64 + (tid & 1);
        float yt = 0.f;
        #pragma unroll
        for (int u = 0; u < 3; ++u)
            #pragma unroll
            for (int v = 0; v < 3; ++v)
                yt += fco[u * 3 + v] * sval[r + u][c + v];
        float e = sval[r + 1][c + 1] - yt;
        float d = __expf(-e * e);
        if ((unsigned)(h0 - 1 + r) >= HH || (unsigned)(w0 - 1 + c) >= WW) d = 0.f;
        sdiff[r][c] = d;
    }
    __syncthreads();

    // ---- phase 3: wave w -> output rows [16w, 16w+16), lane x -> column x ----
    {
        const int y0 = wave * 16;
        const int x  = lane;
        float* dst = yout + (size_t)bc * (HH * WW) + (size_t)(h0 + y0) * WW + (w0 + x);

        float sd0[3], sd1[3], sd2[3];
        float sv0[3], sv1[3], sv2[3];
        float vd0[3], vd1[3], vd2[3];
        #pragma unroll
        for (int b = 0; b < 3; ++b) {
            sd0[b] = sdiff[y0][x + b];
            sv0[b] = sval[y0 + 1][x + 1 + b];
            vd0[b] = sd0[b] * sv0[b];
            sd1[b] = sdiff[y0 + 1][x + b];
            sv1[b] = sval[y0 + 2][x + 1 + b];
            vd1[b] = sd1[b] * sv1[b];
        }
        #pragma unroll
        for (int i = 0; i < 16; ++i) {
            const int y = y0 + i;
            #pragma unroll
            for (int b = 0; b < 3; ++b) {
                sd2[b] = sdiff[y + 2][x + b];
                sv2[b] = sval[y + 3][x + 1 + b];
                vd2[b] = sd2[b] * sv2[b];
            }
            float yt  = fco[0]*sv0[0] + fco[1]*sv0[1] + fco[2]*sv0[2]
                      + fco[3]*sv1[0] + fco[4]*sv1[1] + fco[5]*sv1[2]
                      + fco[6]*sv2[0] + fco[7]*sv2[1] + fco[8]*sv2[2];
            float yd9 = 1e-10f
                      + awk[0]*sd0[0] + awk[1]*sd0[1] + awk[2]*sd0[2]
                      + awk[3]*sd1[0] + awk[4]*sd1[1] + awk[5]*sd1[2]
                      + awk[6]*sd2[0] + awk[7]*sd2[1] + awk[8]*sd2[2];
            float rs  = wk[0]*vd0[0] + wk[1]*vd0[1] + wk[2]*vd0[2]
                      + wk[3]*vd1[0] + wk[4]*vd1[1] + wk[5]*vd1[2]
                      + wk[6]*vd2[0] + wk[7]*vd2[1] + wk[8]*vd2[2];
            float rd  = ws[0]*vd1[0] + ws[1]*vd1[1] + ws[2]*vd1[2];
            float inv = __builtin_amdgcn_rcpf(yd9);
            dst[i * WW] = yt - (rs - rd) * inv;
            #pragma unroll
            for (int b = 0; b < 3; ++b) {
                sd0[b] = sd1[b]; sv0[b] = sv1[b]; vd0[b] = vd1[b];
                sd1[b] = sd2[b]; sv1[b] = sv2[b]; vd1[b] = vd2[b];
            }
        }
    }
}

// ---------------------------------------------------------------------------
extern "C" void kernel_launch(void* const* d_in, const int* in_sizes, int n_in,
                              void* d_out, int out_size, void* d_ws, size_t ws_size,
                              hipStream_t stream) {
    const float* query = (const float*)d_in[0];   // (100,8,64)
    const float* value = (const float*)d_in[1];   // (8,64,256,256)
    // d_in[2..4]: unused scalars
    const float* Wl    = (const float*)d_in[5];   // (18,100)
    const float* bl    = (const float*)d_in[6];   // (18,)
    const float* Wd    = (const float*)d_in[7];   // (100,18)
    const float* bd    = (const float*)d_in[8];   // (100,)

    float* out   = (float*)d_out;
    float* qout  = out;                 // first 100*512 floats
    float* yout  = out + QN * BC;       // then 512*256*256 floats
    float* coef  = (float*)d_ws;        // 512*32 floats = 64 KB

    prep_kernel<<<BC, 128, 0, stream>>>(query, Wl, bl, Wd, bd, qout, coef);

    dim3 grid(WW / 64, HH / 64, BC);
    fused_kernel<<<grid, 256, 0, stream>>>(value, coef, yout);
}